// Round 17
// baseline (390.823 us; speedup 1.0000x reference)
//
#include <hip/hip_runtime.h>
#include <math.h>

#define N_NODES 50000
#define N_PAD 50048                     // 64-row padded
#define E_EDGES 800000
#define E_PAD (E_EDGES + 4 * N_NODES)   // padded srclist capacity (pad to x4)
#define FDIM_IN 128
#define HID_1 32
#define HEADS_1 8
#define H1DIM 256
#define NUM_WALKS 512
#define WALK_LEN 64
#define WINDOW 5
#define NEG_S 10
#define TEMP 0.07f
#define INV_TEMP (1.0f / 0.07f)
#define NEG_SLOPE 0.2f
#define LOG2E 1.44269504f
#define ROW_XW 72                       // 64 fp8-uints + 8 als floats per row

#define SCAN_BLOCKS ((N_NODES + 255) / 256)   // 196

typedef unsigned int uint;
typedef unsigned short ushort;
typedef long long i64_t;
typedef __attribute__((ext_vector_type(8))) short bf16x8;
typedef __attribute__((ext_vector_type(4))) float f32x4;
typedef __attribute__((ext_vector_type(2))) float vf2;

__device__ __forceinline__ float leaky(float v) {
    return fmaxf(v, v * NEG_SLOPE);
}

__device__ __forceinline__ float bfl(uint u) { return __uint_as_float(u << 16); }
__device__ __forceinline__ float bfh(uint u) { return __uint_as_float(u & 0xffff0000u); }

__device__ __forceinline__ ushort f2bf(float x) {
    uint u = __float_as_uint(x);
    u = u + 0x7fffu + ((u >> 16) & 1u);   // round-to-nearest-even
    return (ushort)(u >> 16);
}

// pack 4 f32 -> 4 fp8(e4m3) in one uint (HW converter; self-consistent with decode)
__device__ __forceinline__ uint pk4fp8(float a, float b, float c, float d) {
    int u = __builtin_amdgcn_cvt_pk_fp8_f32(a, b, 0, false);
    u = __builtin_amdgcn_cvt_pk_fp8_f32(c, d, u, true);
    return (uint)u;
}

// ---------------- CSR build (rows padded to multiples of 4 with sentinel) ----------------

__global__ void deg_kernel(const int* __restrict__ ei, int* __restrict__ deg) {
    int e = blockIdx.x * blockDim.x + threadIdx.x;
    if (e < E_EDGES) atomicAdd(&deg[ei[E_EDGES + e]], 1);
}

__global__ __launch_bounds__(256) void scan_a(const int* __restrict__ deg,
                                              int* __restrict__ excl,
                                              int* __restrict__ bsum) {
    __shared__ int s[256];
    int t = threadIdx.x;
    int i = blockIdx.x * 256 + t;
    int d = (i < N_NODES) ? deg[i] : 0;
    int v = (d + 3) & ~3;                // padded degree
    s[t] = v;
    __syncthreads();
    for (int off = 1; off < 256; off <<= 1) {
        int tmp = (t >= off) ? s[t - off] : 0;
        __syncthreads();
        s[t] += tmp;
        __syncthreads();
    }
    if (i < N_NODES) excl[i] = s[t] - v;
    if (t == 255) bsum[blockIdx.x] = s[255];
}

__global__ __launch_bounds__(256) void scan_b(int* __restrict__ bsum) {
    __shared__ int s[256];
    int t = threadIdx.x;
    int v = (t < SCAN_BLOCKS) ? bsum[t] : 0;
    s[t] = v;
    __syncthreads();
    for (int off = 1; off < 256; off <<= 1) {
        int tmp = (t >= off) ? s[t - off] : 0;
        __syncthreads();
        s[t] += tmp;
        __syncthreads();
    }
    if (t < SCAN_BLOCKS) bsum[t] = s[t] - v;   // exclusive
}

__global__ void scan_c2(const int* __restrict__ deg,
                        int* __restrict__ excl, const int* __restrict__ bsum,
                        int* __restrict__ row_start) {
    int i = blockIdx.x * blockDim.x + threadIdx.x;
    if (i < N_NODES) {
        int rs = excl[i] + bsum[i >> 8];
        row_start[i] = rs;
        if (i == N_NODES - 1) row_start[N_NODES] = rs + ((deg[i] + 3) & ~3);
    }
}

__global__ void fill_sent_kernel(int* __restrict__ p, int n) {
    int i = blockIdx.x * blockDim.x + threadIdx.x;
    if (i < n) p[i] = N_NODES;           // sentinel node id
}

// sentinel row tail: als = -1e30 so exp2 -> 0 for padded edges
__global__ void sent_al_kernel(uint* __restrict__ xw8) {
    int t = threadIdx.x;
    if (t < 8) xw8[(size_t)N_NODES * ROW_XW + 64 + t] = __float_as_uint(-1e30f);
}

__global__ void bucket_kernel(const int* __restrict__ ei,
                              const int* __restrict__ row_start,
                              int* __restrict__ cursor,
                              int* __restrict__ srclist) {
    int e = blockIdx.x * blockDim.x + threadIdx.x;
    if (e >= E_EDGES) return;
    int dst = ei[E_EDGES + e];
    int pos = atomicAdd(&cursor[dst], 1);
    srclist[row_start[dst] + pos] = ei[e];
}

// ---------------- dtype conversion ----------------

__global__ void f32_to_bf16_kernel(const float* __restrict__ src, uint* __restrict__ dst, int n4) {
    int i = blockIdx.x * blockDim.x + threadIdx.x;
    if (i >= n4) return;
    float4 v = ((const float4*)src)[i];
    uint2 p;
    p.x = (uint)f2bf(v.x) | ((uint)f2bf(v.y) << 16);
    p.y = (uint)f2bf(v.z) | ((uint)f2bf(v.w) << 16);
    ((uint2*)dst)[i] = p;
}

// W[K][256] fp32 -> Wt[256][K] bf16
__global__ void wtrans_kernel(const float* __restrict__ W, ushort* __restrict__ Wt, int K) {
    int tid = blockIdx.x * blockDim.x + threadIdx.x;
    if (tid >= 256 * K) return;
    int k = tid >> 8, n = tid & 255;
    Wt[n * K + k] = f2bf(W[k * 256 + n]);
}

// ---- MFMA GEMM, 64-row blocks, fused attention-logit epilogue (register-based) ----
// Y8 rows: [0..63] fp8 data, [64..71] als floats (log2e-scaled). ald -> array.
template<int K, int H>
__global__ __launch_bounds__(256) void mfma_gemm64(
        const ushort* __restrict__ A,    // [Mpad][K] bf16
        const ushort* __restrict__ Wt,   // [256][K] bf16 (transposed)
        uint* __restrict__ Y8,           // [M][ROW_XW]
        const float* __restrict__ a_src, // [256]
        const float* __restrict__ a_dst,
        float* __restrict__ ald) {
    constexpr int KP = K + 8;
    constexpr int K8 = K / 8;
    __shared__ __align__(16) ushort As[64 * KP];   // K=128:17.4KB, K=256:33.8KB
    __shared__ float sals[64][5], sald[64][5];     // used for H==1 cross-wave reduce
    const int m0 = blockIdx.x * 64;
    const int t = threadIdx.x;
    const uint4* Ag = (const uint4*)(A + (size_t)m0 * K);
    uint4* As4 = (uint4*)As;
    for (int i = t; i < 64 * K8; i += 256) {
        int r = i / K8, c8 = i % K8;
        As4[r * (K8 + 1) + c8] = Ag[i];
    }
    __syncthreads();
    const int wv = __builtin_amdgcn_readfirstlane(t >> 6);
    const int lane = t & 63;
    const int n0 = wv * 64;
    const int mrow = lane & 15, q = lane >> 4;
    f32x4 acc[4][4];
#pragma unroll
    for (int mt = 0; mt < 4; mt++)
#pragma unroll
        for (int i = 0; i < 4; i++) acc[mt][i] = (f32x4){0.f, 0.f, 0.f, 0.f};
#pragma unroll
    for (int k0 = 0; k0 < K; k0 += 32) {
        bf16x8 a[4], b[4];
#pragma unroll
        for (int mt = 0; mt < 4; mt++)
            a[mt] = *(const bf16x8*)(As + (mt * 16 + mrow) * KP + k0 + q * 8);
#pragma unroll
        for (int i = 0; i < 4; i++)
            b[i] = *(const bf16x8*)(Wt + (uint)(n0 + i * 16 + mrow) * K + k0 + q * 8);
#pragma unroll
        for (int mt = 0; mt < 4; mt++)
#pragma unroll
            for (int i = 0; i < 4; i++)
                acc[mt][i] = __builtin_amdgcn_mfma_f32_16x16x32_bf16(a[mt], b[i], acc[mt][i], 0, 0, 0);
    }
    // ---- fused attention-logit epilogue (registers + 16-lane butterflies) ----
    {
        float as[4], ad[4];
#pragma unroll
        for (int i = 0; i < 4; i++) {
            as[i] = a_src[n0 + i * 16 + mrow];
            ad[i] = a_dst[n0 + i * 16 + mrow];
        }
#pragma unroll
        for (int mt = 0; mt < 4; mt++) {
#pragma unroll
            for (int r = 0; r < 4; r++) {
                const int row = m0 + mt * 16 + q * 4 + r;
                if (H == 8) {
                    float ps0 = acc[mt][0][r] * as[0] + acc[mt][1][r] * as[1];
                    float ps1 = acc[mt][2][r] * as[2] + acc[mt][3][r] * as[3];
                    float pd0 = acc[mt][0][r] * ad[0] + acc[mt][1][r] * ad[1];
                    float pd1 = acc[mt][2][r] * ad[2] + acc[mt][3][r] * ad[3];
#pragma unroll
                    for (int o = 1; o < 16; o <<= 1) {
                        ps0 += __shfl_xor(ps0, o, 64); ps1 += __shfl_xor(ps1, o, 64);
                        pd0 += __shfl_xor(pd0, o, 64); pd1 += __shfl_xor(pd1, o, 64);
                    }
                    if (mrow == 0 && row < N_NODES) {
                        uint* tail = Y8 + (size_t)row * ROW_XW + 64;
                        tail[2 * wv] = __float_as_uint(ps0 * LOG2E);
                        tail[2 * wv + 1] = __float_as_uint(ps1 * LOG2E);
                        ald[row * 8 + 2 * wv] = pd0 * LOG2E;
                        ald[row * 8 + 2 * wv + 1] = pd1 * LOG2E;
                    }
                } else {
                    float ps = acc[mt][0][r] * as[0] + acc[mt][1][r] * as[1]
                             + acc[mt][2][r] * as[2] + acc[mt][3][r] * as[3];
                    float pd = acc[mt][0][r] * ad[0] + acc[mt][1][r] * ad[1]
                             + acc[mt][2][r] * ad[2] + acc[mt][3][r] * ad[3];
#pragma unroll
                    for (int o = 1; o < 16; o <<= 1) {
                        ps += __shfl_xor(ps, o, 64); pd += __shfl_xor(pd, o, 64);
                    }
                    if (mrow == 0) {
                        sals[mt * 16 + q * 4 + r][wv] = ps;
                        sald[mt * 16 + q * 4 + r][wv] = pd;
                    }
                }
            }
        }
    }
    __syncthreads();                     // A-tile dead; sals complete
    if (H == 1 && t < 64) {
        const int row = m0 + t;
        if (row < N_NODES) {
            float s = (sals[t][0] + sals[t][1] + sals[t][2] + sals[t][3]) * LOG2E;
            Y8[(size_t)row * ROW_XW + 64] = __float_as_uint(s);
            ald[row] = (sald[t][0] + sald[t][1] + sald[t][2] + sald[t][3]) * LOG2E;
        }
    }
    float* S = (float*)As + wv * 16 * 68;   // 16 rows x 68 floats, wave-private
    const int prow = lane >> 2, pj = lane & 3;   // pack: lane -> (row-in-tile, uint4 j)
#pragma unroll
    for (int mt = 0; mt < 4; mt++) {
#pragma unroll
        for (int i = 0; i < 4; i++)
#pragma unroll
            for (int r = 0; r < 4; r++)
                S[(q * 4 + r) * 68 + i * 16 + mrow] = acc[mt][i][r];
        // wave-internal LDS ordering: no barrier needed
        const float* cp = S + prow * 68 + pj * 16;
        uint4 o;
        o.x = pk4fp8(cp[0],  cp[1],  cp[2],  cp[3]);
        o.y = pk4fp8(cp[4],  cp[5],  cp[6],  cp[7]);
        o.z = pk4fp8(cp[8],  cp[9],  cp[10], cp[11]);
        o.w = pk4fp8(cp[12], cp[13], cp[14], cp[15]);
        const int row = m0 + mt * 16 + prow;
        if (row < N_NODES)
            ((uint4*)(Y8 + (size_t)row * ROW_XW))[wv * 4 + pj] = o;
    }
}

#define UN 4

// layer-1 gather: tail-packed als (single gather stream), exp2 logits, packed accum
__global__ __launch_bounds__(256) void gat_gather1(
        const int* __restrict__ row_start, const int* __restrict__ srclist,
        const float* __restrict__ ald,
        const uint* __restrict__ xw8,                    // ROW_XW uints/row
        const float* __restrict__ bias,
        ushort* __restrict__ emb1b) {                    // [N][256] bf16
    const int wid = __builtin_amdgcn_readfirstlane(blockIdx.x * 4 + (threadIdx.x >> 6));
    const uint lane = threadIdx.x & 63;
    const uint h = lane >> 3;
    const float ald_n = ald[wid * HEADS_1 + h];
    const int beg = row_start[wid], end = row_start[wid + 1];
    const uint wbase = (uint)wid * ROW_XW;

    float als0 = __uint_as_float(xw8[wbase + 64 + h]);
    float ex0 = __builtin_amdgcn_exp2f(leaky(als0 + ald_n));
    uint u = xw8[wbase + lane];
    vf2 lo = __builtin_amdgcn_cvt_pk_f32_fp8((int)u, false);
    vf2 hi = __builtin_amdgcn_cvt_pk_f32_fp8((int)u, true);
    float den = ex0;
    vf2 exv0 = {ex0, ex0};
    vf2 a01 = exv0 * lo, a23 = exv0 * hi;

    for (int i = beg; i < end; i += UN) {
        uint sb[UN]; uint rr[UN]; float ee[UN];
#pragma unroll
        for (int j = 0; j < UN; j++) sb[j] = (uint)srclist[i + j] * ROW_XW;
#pragma unroll
        for (int j = 0; j < UN; j++) rr[j] = xw8[sb[j] + lane];
#pragma unroll
        for (int j = 0; j < UN; j++) ee[j] = __uint_as_float(xw8[sb[j] + 64 + h]);
#pragma unroll
        for (int j = 0; j < UN; j++) {
            float ex = __builtin_amdgcn_exp2f(leaky(ee[j] + ald_n));   // sentinel -> 0
            vf2 l2 = __builtin_amdgcn_cvt_pk_f32_fp8((int)rr[j], false);
            vf2 h2 = __builtin_amdgcn_cvt_pk_f32_fp8((int)rr[j], true);
            den += ex;
            vf2 exv = {ex, ex};
            a01 += exv * l2;
            a23 += exv * h2;
        }
    }
    float inv = 1.f / den;
    float4 bv = ((const float4*)bias)[lane];
    float4 r;
    r.x = a01[0] * inv + bv.x; r.y = a01[1] * inv + bv.y;
    r.z = a23[0] * inv + bv.z; r.w = a23[1] * inv + bv.w;
    r.x = r.x > 0.f ? r.x : __expf(r.x) - 1.f;
    r.y = r.y > 0.f ? r.y : __expf(r.y) - 1.f;
    r.z = r.z > 0.f ? r.z : __expf(r.z) - 1.f;
    r.w = r.w > 0.f ? r.w : __expf(r.w) - 1.f;
    uint2 p;
    p.x = (uint)f2bf(r.x) | ((uint)f2bf(r.y) << 16);
    p.y = (uint)f2bf(r.z) | ((uint)f2bf(r.w) << 16);
    ((uint2*)emb1b)[((uint)wid << 6) + lane] = p;
}

// layer-2 gather fused with normalize + fp8 pack of embn
__global__ __launch_bounds__(256) void gat_gather2(
        const int* __restrict__ row_start, const int* __restrict__ srclist,
        const float* __restrict__ ald,
        const uint* __restrict__ xw8,                    // ROW_XW uints/row
        const float* __restrict__ bias,
        const ushort* __restrict__ emb1b,                // [N][256] bf16
        uint* __restrict__ embn8) {                      // [N][512] fp8, 128 uints/row
    const int wid = __builtin_amdgcn_readfirstlane(blockIdx.x * 4 + (threadIdx.x >> 6));
    const uint lane = threadIdx.x & 63;
    const float ald_n = ald[wid];
    const int beg = row_start[wid], end = row_start[wid + 1];
    const uint wbase = (uint)wid * ROW_XW;

    float als0 = __uint_as_float(xw8[wbase + 64]);
    float ex0 = __builtin_amdgcn_exp2f(leaky(als0 + ald_n));
    uint u = xw8[wbase + lane];
    vf2 lo = __builtin_amdgcn_cvt_pk_f32_fp8((int)u, false);
    vf2 hi = __builtin_amdgcn_cvt_pk_f32_fp8((int)u, true);
    float den = ex0;
    vf2 exv0 = {ex0, ex0};
    vf2 a01 = exv0 * lo, a23 = exv0 * hi;

    for (int i = beg; i < end; i += UN) {
        uint sb[UN]; uint rr[UN]; float ee[UN];
#pragma unroll
        for (int j = 0; j < UN; j++) sb[j] = (uint)srclist[i + j] * ROW_XW;
#pragma unroll
        for (int j = 0; j < UN; j++) rr[j] = xw8[sb[j] + lane];
#pragma unroll
        for (int j = 0; j < UN; j++) ee[j] = __uint_as_float(xw8[sb[j] + 64]);
#pragma unroll
        for (int j = 0; j < UN; j++) {
            float ex = __builtin_amdgcn_exp2f(leaky(ee[j] + ald_n));   // sentinel -> 0
            vf2 l2 = __builtin_amdgcn_cvt_pk_f32_fp8((int)rr[j], false);
            vf2 h2 = __builtin_amdgcn_cvt_pk_f32_fp8((int)rr[j], true);
            den += ex;
            vf2 exv = {ex, ex};
            a01 += exv * l2;
            a23 += exv * h2;
        }
    }
    float inv = 1.f / den;
    float4 bv = ((const float4*)bias)[lane];
    float4 e2;
    e2.x = a01[0] * inv + bv.x; e2.y = a01[1] * inv + bv.y;
    e2.z = a23[0] * inv + bv.z; e2.w = a23[1] * inv + bv.w;
    uint2 u1 = ((const uint2*)emb1b)[((uint)wid << 6) + lane];
    float4 e1;
    e1.x = bfl(u1.x); e1.y = bfh(u1.x); e1.z = bfl(u1.y); e1.w = bfh(u1.y);

    float ssum = e1.x * e1.x + e1.y * e1.y + e1.z * e1.z + e1.w * e1.w
               + e2.x * e2.x + e2.y * e2.y + e2.z * e2.z + e2.w * e2.w;
#pragma unroll
    for (int o = 32; o > 0; o >>= 1) ssum += __shfl_xor(ssum, o, 64);
    float innv = 1.f / fmaxf(sqrtf(ssum), 1e-8f);

    uint p1 = pk4fp8(e1.x * innv, e1.y * innv, e1.z * innv, e1.w * innv);
    uint p2 = pk4fp8(e2.x * innv, e2.y * innv, e2.z * innv, e2.w * innv);
    embn8[((uint)wid << 7) + lane] = p1;        // dims 0..255   (emb1 part)
    embn8[((uint)wid << 7) + 64 + lane] = p2;   // dims 256..511 (emb2 part)
}

// ---------------- MFMA contrastive loss (fp8) ----------------

#define ANCH 16                         // anchors per block (walk segment)
#define MAXROWS (ANCH + 2 * WINDOW)     // 26 LDS rows max
#define ROWU 130                        // 520 B row stride (2 banks mod 32, conflict-free)

// one block per 16-anchor segment, 768 threads = 12 waves, one tile-job per wave.
__global__ __launch_bounds__(768) void loss_mfma_kernel(
        const uint* __restrict__ embn8,    // [N][512] fp8, 128 uints/row
        const int* __restrict__ walks, const int* __restrict__ negs,
        float* __restrict__ out) {
    __shared__ __align__(16) uint srows8[MAXROWS * ROWU];   // 13.5 KB
    __shared__ int wids[MAXROWS];
    __shared__ int snid[160];
    __shared__ float possum[16];
    __shared__ float negsum[16];
    const int blk = blockIdx.x;
    const int b = blk >> 2;                  // walk
    const int l0 = (blk & 3) * ANCH;         // first anchor of segment
    const int base = (l0 - WINDOW) > 0 ? (l0 - WINDOW) : 0;
    const int hi = (l0 + ANCH - 1 + WINDOW) < (WALK_LEN - 1) ? (l0 + ANCH - 1 + WINDOW) : (WALK_LEN - 1);
    const int cnt = hi - base + 1;           // 21..26
    const int t = threadIdx.x;
    const int w = __builtin_amdgcn_readfirstlane(t >> 6);   // 0..11 = this wave's job
    const int lane = t & 63;
    if (t < cnt) wids[t] = walks[b * WALK_LEN + base + t];
    if (t >= 64 && t < 64 + 160) snid[t - 64] = negs[(b * WALK_LEN + l0) * NEG_S + (t - 64)];
    if (t >= 224 && t < 240) { possum[t - 224] = 0.f; negsum[t - 224] = 0.f; }
    __syncthreads();
    for (int r = w; r < cnt; r += 12)
        ((uint2*)(srows8 + r * ROWU))[lane] = ((const uint2*)(embn8 + ((uint)wids[r] << 7)))[lane];
    __syncthreads();

    const int mrow = lane & 15, q = lane >> 4;
    const int arow = (l0 - base) + mrow;     // LDS row of anchor #mrow
    const char* embc = (const char*)embn8;   // byte rows, stride 512
    const char* ap = (const char*)(srows8 + arow * ROWU) + q * 8;

    const int job = w;
    f32x4 acc0 = {0.f, 0.f, 0.f, 0.f};
    f32x4 acc1 = {0.f, 0.f, 0.f, 0.f};
    if (job < 10) {
        // ---- neg tile: cands c = 16*job .. +15, col = mrow ----
        const int c = job * 16 + mrow;
        const int node = snid[c];
        const char* bp = embc + (((uint)node << 9) + (uint)(q * 8));
#pragma unroll
        for (int k0 = 0; k0 < 256; k0 += 32) {
            i64_t a0 = *(const i64_t*)(ap + k0);
            i64_t b0 = *(const i64_t*)(bp + k0);
            acc0 = __builtin_amdgcn_mfma_f32_16x16x32_fp8_fp8(a0, b0, acc0, 0, 0, 0);
            i64_t a1 = *(const i64_t*)(ap + k0 + 256);
            i64_t b1 = *(const i64_t*)(bp + k0 + 256);
            acc1 = __builtin_amdgcn_mfma_f32_16x16x32_fp8_fp8(a1, b1, acc1, 0, 0, 0);
        }
        const int owner = c / 10;
#pragma unroll
        for (int reg = 0; reg < 4; reg++) {
            const int a_local = q * 4 + reg;
            float e = 0.f;
            if (owner == a_local) {
                const int l_a = l0 + a_local;
                bool msk = false;
#pragma unroll
                for (int dj = -WINDOW; dj <= WINDOW; dj++) {
                    if (dj == 0) continue;
                    int p = l_a + dj;
                    if (p >= 0 && p < WALK_LEN && wids[p - base] == node) msk = true;
                }
                if (!msk) e = __expf((acc0[reg] + acc1[reg]) * INV_TEMP);
            }
#pragma unroll
            for (int o = 1; o < 16; o <<= 1) e += __shfl_xor(e, o, 64);
            if (mrow == 0 && e != 0.f) atomicAdd(&negsum[a_local], e);
        }
    } else {
        // ---- pos tile: LDS rows r = 16*(job-10) .. +15 ----
        const int r = (job - 10) * 16 + mrow;
        const int rc = r < (cnt - 1) ? r : (cnt - 1);
        const char* bp = (const char*)(srows8 + rc * ROWU) + q * 8;
#pragma unroll
        for (int k0 = 0; k0 < 256; k0 += 32) {
            i64_t a0 = *(const i64_t*)(ap + k0);
            i64_t b0 = *(const i64_t*)(bp + k0);
            acc0 = __builtin_amdgcn_mfma_f32_16x16x32_fp8_fp8(a0, b0, acc0, 0, 0, 0);
            i64_t a1 = *(const i64_t*)(ap + k0 + 256);
            i64_t b1 = *(const i64_t*)(bp + k0 + 256);
            acc1 = __builtin_amdgcn_mfma_f32_16x16x32_fp8_fp8(a1, b1, acc1, 0, 0, 0);
        }
        const int pg = base + r;                 // walk position of this row
#pragma unroll
        for (int reg = 0; reg < 4; reg++) {
            const int a_local = q * 4 + reg;
            const int l_a = l0 + a_local;
            const int d = pg - l_a;
            bool use = (r < cnt) && (d != 0) && (d >= -WINDOW) && (d <= WINDOW);
            float e = use ? __expf((acc0[reg] + acc1[reg]) * INV_TEMP) : 0.f;
#pragma unroll
            for (int o = 1; o < 16; o <<= 1) e += __shfl_xor(e, o, 64);
            if (mrow == 0 && e != 0.f) atomicAdd(&possum[a_local], e);
        }
    }
    __syncthreads();
    if (t < 16) {
        float term = logf(1.f + negsum[t] / possum[t]);   // possum > 0 always
#pragma unroll
        for (int o = 8; o > 0; o >>= 1) term += __shfl_xor(term, o, 64);
        if (t == 0) atomicAdd(out, term);
    }
}

extern "C" void kernel_launch(void* const* d_in, const int* in_sizes, int n_in,
                              void* d_out, int out_size, void* d_ws, size_t ws_size,
                              hipStream_t stream) {
    const float* x      = (const float*)d_in[0];
    const int*   ei     = (const int*)d_in[1];
    const int*   walks  = (const int*)d_in[2];
    const int*   negs   = (const int*)d_in[3];
    const float* W1     = (const float*)d_in[4];
    const float* a_src1 = (const float*)d_in[5];
    const float* a_dst1 = (const float*)d_in[6];
    const float* b1     = (const float*)d_in[7];
    const float* W2     = (const float*)d_in[8];
    const float* a_src2 = (const float*)d_in[9];
    const float* a_dst2 = (const float*)d_in[10];
    const float* b2     = (const float*)d_in[11];
    float* out = (float*)d_out;

    float* ws = (float*)d_ws;
    size_t off = 0;
    float* r_xw8   = ws + off; off += (size_t)(N_NODES + 1) * ROW_XW; // [N+1][ROW_XW] fp8+als
    float* r_emb1b = ws + off; off += (size_t)N_PAD * 128;         // [Npad][256] bf16
    float* r_embn8 = ws + off; off += (size_t)N_NODES * 128;       // [N][512] fp8
    float* r_xb    = ws + off; off += (size_t)N_PAD * 64;          // [Npad][128] bf16
    float* r_wt1   = ws + off; off += 256 * 64;                    // [256][128] bf16
    float* r_wt2   = ws + off; off += 256 * 128;                   // [256][256] bf16
    float* ald1  = ws + off; off += N_NODES * HEADS_1;
    float* ald2  = ws + off; off += N_NODES;
    int* deg       = (int*)(ws + off); off += N_NODES;
    int* excl      = (int*)(ws + off); off += N_NODES;
    int* bsum      = (int*)(ws + off); off += 256;
    int* row_start = (int*)(ws + off); off += N_NODES + 1;
    int* cursor    = (int*)(ws + off); off += N_NODES;
    int* srclist   = (int*)(ws + off); off += E_PAD;
    uint*   xw8   = (uint*)r_xw8;
    ushort* emb1b = (ushort*)r_emb1b;
    uint*   embn8 = (uint*)r_embn8;
    ushort* xb    = (ushort*)r_xb;
    ushort* wt1   = (ushort*)r_wt1;
    ushort* wt2   = (ushort*)r_wt2;

    hipMemsetAsync(out, 0, sizeof(float) * out_size, stream);
    hipMemsetAsync(deg, 0, sizeof(int) * N_NODES, stream);
    hipMemsetAsync(cursor, 0, sizeof(int) * N_NODES, stream);

    // ---- CSR build (padded rows, sentinel-filled; shared by both layers) ----
    deg_kernel<<<(E_EDGES + 255) / 256, 256, 0, stream>>>(ei, deg);
    scan_a<<<SCAN_BLOCKS, 256, 0, stream>>>(deg, excl, bsum);
    scan_b<<<1, 256, 0, stream>>>(bsum);
    scan_c2<<<SCAN_BLOCKS, 256, 0, stream>>>(deg, excl, bsum, row_start);
    fill_sent_kernel<<<(E_PAD + 255) / 256, 256, 0, stream>>>(srclist, E_PAD);
    bucket_kernel<<<(E_EDGES + 255) / 256, 256, 0, stream>>>(ei, row_start, cursor, srclist);
    sent_al_kernel<<<1, 64, 0, stream>>>(xw8);

    // ---- bf16 conversions ----
    f32_to_bf16_kernel<<<(N_NODES * FDIM_IN / 4 + 255) / 256, 256, 0, stream>>>(
        x, (uint*)xb, N_NODES * FDIM_IN / 4);
    wtrans_kernel<<<(256 * 128 + 255) / 256, 256, 0, stream>>>(W1, wt1, 128);
    wtrans_kernel<<<(256 * 256 + 255) / 256, 256, 0, stream>>>(W2, wt2, 256);

    // ---- layer 1 (heads=8, hid=32), fused als(tail)/ald epilogue ----
    mfma_gemm64<128, HEADS_1><<<N_PAD / 64, 256, 0, stream>>>(
        xb, wt1, xw8, a_src1, a_dst1, ald1);
    gat_gather1<<<N_NODES / 4, 256, 0, stream>>>(
        row_start, srclist, ald1, xw8, b1, emb1b);

    // ---- layer 2 (heads=1, hid=256), fused als(tail)/ald + normalize + fp8 pack ----
    mfma_gemm64<256, 1><<<N_PAD / 64, 256, 0, stream>>>(
        emb1b, wt2, xw8, a_src2, a_dst2, ald2);
    gat_gather2<<<N_NODES / 4, 256, 0, stream>>>(
        row_start, srclist, ald2, xw8, b2, emb1b, embn8);

    // ---- contrastive loss (fp8 MFMA, one job per wave) ----
    loss_mfma_kernel<<<NUM_WALKS * 4, 768, 0, stream>>>(embn8, walks, negs, out);
}

// Round 18
// 374.024 us; speedup vs baseline: 1.0449x; 1.0449x over previous
//
#include <hip/hip_runtime.h>
#include <math.h>

#define N_NODES 50000
#define N_PAD 50048                     // 64-row padded
#define E_EDGES 800000
#define E_PAD (E_EDGES + 4 * N_NODES)   // padded srclist capacity (pad to x4)
#define FDIM_IN 128
#define HID_1 32
#define HEADS_1 8
#define H1DIM 256
#define NUM_WALKS 512
#define WALK_LEN 64
#define WINDOW 5
#define NEG_S 10
#define TEMP 0.07f
#define INV_TEMP (1.0f / 0.07f)
#define NEG_SLOPE 0.2f
#define LOG2E 1.44269504f

#define SCAN_BLOCKS ((N_NODES + 255) / 256)   // 196

typedef unsigned int uint;
typedef unsigned short ushort;
typedef long long i64_t;
typedef __attribute__((ext_vector_type(8))) short bf16x8;
typedef __attribute__((ext_vector_type(4))) float f32x4;
typedef __attribute__((ext_vector_type(2))) float vf2;

__device__ __forceinline__ float leaky(float v) {
    return fmaxf(v, v * NEG_SLOPE);
}

__device__ __forceinline__ float bfl(uint u) { return __uint_as_float(u << 16); }
__device__ __forceinline__ float bfh(uint u) { return __uint_as_float(u & 0xffff0000u); }

__device__ __forceinline__ ushort f2bf(float x) {
    uint u = __float_as_uint(x);
    u = u + 0x7fffu + ((u >> 16) & 1u);   // round-to-nearest-even
    return (ushort)(u >> 16);
}

// pack 4 f32 -> 4 fp8(e4m3) in one uint (HW converter; self-consistent with decode)
__device__ __forceinline__ uint pk4fp8(float a, float b, float c, float d) {
    int u = __builtin_amdgcn_cvt_pk_fp8_f32(a, b, 0, false);
    u = __builtin_amdgcn_cvt_pk_fp8_f32(c, d, u, true);
    return (uint)u;
}

// ---------------- CSR build (rows padded to multiples of 4 with sentinel) ----------------

__global__ void deg_kernel(const int* __restrict__ ei, int* __restrict__ deg) {
    int e = blockIdx.x * blockDim.x + threadIdx.x;
    if (e < E_EDGES) atomicAdd(&deg[ei[E_EDGES + e]], 1);
}

__global__ __launch_bounds__(256) void scan_a(const int* __restrict__ deg,
                                              int* __restrict__ excl,
                                              int* __restrict__ bsum) {
    __shared__ int s[256];
    int t = threadIdx.x;
    int i = blockIdx.x * 256 + t;
    int d = (i < N_NODES) ? deg[i] : 0;
    int v = (d + 3) & ~3;                // padded degree
    s[t] = v;
    __syncthreads();
    for (int off = 1; off < 256; off <<= 1) {
        int tmp = (t >= off) ? s[t - off] : 0;
        __syncthreads();
        s[t] += tmp;
        __syncthreads();
    }
    if (i < N_NODES) excl[i] = s[t] - v;
    if (t == 255) bsum[blockIdx.x] = s[255];
}

__global__ __launch_bounds__(256) void scan_b(int* __restrict__ bsum) {
    __shared__ int s[256];
    int t = threadIdx.x;
    int v = (t < SCAN_BLOCKS) ? bsum[t] : 0;
    s[t] = v;
    __syncthreads();
    for (int off = 1; off < 256; off <<= 1) {
        int tmp = (t >= off) ? s[t - off] : 0;
        __syncthreads();
        s[t] += tmp;
        __syncthreads();
    }
    if (t < SCAN_BLOCKS) bsum[t] = s[t] - v;   // exclusive
}

__global__ void scan_c2(const int* __restrict__ deg,
                        int* __restrict__ excl, const int* __restrict__ bsum,
                        int* __restrict__ row_start) {
    int i = blockIdx.x * blockDim.x + threadIdx.x;
    if (i < N_NODES) {
        int rs = excl[i] + bsum[i >> 8];
        row_start[i] = rs;
        if (i == N_NODES - 1) row_start[N_NODES] = rs + ((deg[i] + 3) & ~3);
    }
}

__global__ void fill_sent_kernel(int* __restrict__ p, int n) {
    int i = blockIdx.x * blockDim.x + threadIdx.x;
    if (i < n) p[i] = N_NODES;           // sentinel node id
}

__global__ void sent_al_kernel(float* __restrict__ als1, float* __restrict__ als2) {
    int t = threadIdx.x;
    if (t < HEADS_1) als1[N_NODES * HEADS_1 + t] = -1e30f;
    if (t == HEADS_1) als2[N_NODES] = -1e30f;
}

__global__ void bucket_kernel(const int* __restrict__ ei,
                              const int* __restrict__ row_start,
                              int* __restrict__ cursor,
                              int* __restrict__ srclist) {
    int e = blockIdx.x * blockDim.x + threadIdx.x;
    if (e >= E_EDGES) return;
    int dst = ei[E_EDGES + e];
    int pos = atomicAdd(&cursor[dst], 1);
    srclist[row_start[dst] + pos] = ei[e];
}

// ---------------- dtype conversion ----------------

__global__ void f32_to_bf16_kernel(const float* __restrict__ src, uint* __restrict__ dst, int n4) {
    int i = blockIdx.x * blockDim.x + threadIdx.x;
    if (i >= n4) return;
    float4 v = ((const float4*)src)[i];
    uint2 p;
    p.x = (uint)f2bf(v.x) | ((uint)f2bf(v.y) << 16);
    p.y = (uint)f2bf(v.z) | ((uint)f2bf(v.w) << 16);
    ((uint2*)dst)[i] = p;
}

// W[K][256] fp32 -> Wt[256][K] bf16
__global__ void wtrans_kernel(const float* __restrict__ W, ushort* __restrict__ Wt, int K) {
    int tid = blockIdx.x * blockDim.x + threadIdx.x;
    if (tid >= 256 * K) return;
    int k = tid >> 8, n = tid & 255;
    Wt[n * K + k] = f2bf(W[k * 256 + n]);
}

// ---- MFMA GEMM, 64-row blocks, fused attention-logit epilogue (register-based) ----
// Y8[M][256] (fp8) = A[M][K]*W[K][256]; als/ald[n][h] = dot(C_row, a_src/a_dst)*log2e
template<int K, int H>
__global__ __launch_bounds__(256) void mfma_gemm64(
        const ushort* __restrict__ A,    // [Mpad][K] bf16
        const ushort* __restrict__ Wt,   // [256][K] bf16 (transposed)
        uint* __restrict__ Y8,           // [M][256] fp8, 64 uints/row
        const float* __restrict__ a_src, // [256]
        const float* __restrict__ a_dst,
        float* __restrict__ als, float* __restrict__ ald) {
    constexpr int KP = K + 8;
    constexpr int K8 = K / 8;
    __shared__ __align__(16) ushort As[64 * KP];   // K=128:17.4KB, K=256:33.8KB
    __shared__ float sals[64][5], sald[64][5];     // used for H==1 cross-wave reduce
    const int m0 = blockIdx.x * 64;
    const int t = threadIdx.x;
    const uint4* Ag = (const uint4*)(A + (size_t)m0 * K);
    uint4* As4 = (uint4*)As;
    for (int i = t; i < 64 * K8; i += 256) {
        int r = i / K8, c8 = i % K8;
        As4[r * (K8 + 1) + c8] = Ag[i];
    }
    __syncthreads();
    const int wv = __builtin_amdgcn_readfirstlane(t >> 6);
    const int lane = t & 63;
    const int n0 = wv * 64;
    const int mrow = lane & 15, q = lane >> 4;
    f32x4 acc[4][4];
#pragma unroll
    for (int mt = 0; mt < 4; mt++)
#pragma unroll
        for (int i = 0; i < 4; i++) acc[mt][i] = (f32x4){0.f, 0.f, 0.f, 0.f};
#pragma unroll
    for (int k0 = 0; k0 < K; k0 += 32) {
        bf16x8 a[4], b[4];
#pragma unroll
        for (int mt = 0; mt < 4; mt++)
            a[mt] = *(const bf16x8*)(As + (mt * 16 + mrow) * KP + k0 + q * 8);
#pragma unroll
        for (int i = 0; i < 4; i++)
            b[i] = *(const bf16x8*)(Wt + (uint)(n0 + i * 16 + mrow) * K + k0 + q * 8);
#pragma unroll
        for (int mt = 0; mt < 4; mt++)
#pragma unroll
            for (int i = 0; i < 4; i++)
                acc[mt][i] = __builtin_amdgcn_mfma_f32_16x16x32_bf16(a[mt], b[i], acc[mt][i], 0, 0, 0);
    }
    // ---- fused attention-logit epilogue (registers + 16-lane butterflies) ----
    {
        float as[4], ad[4];
#pragma unroll
        for (int i = 0; i < 4; i++) {
            as[i] = a_src[n0 + i * 16 + mrow];
            ad[i] = a_dst[n0 + i * 16 + mrow];
        }
#pragma unroll
        for (int mt = 0; mt < 4; mt++) {
#pragma unroll
            for (int r = 0; r < 4; r++) {
                const int row = m0 + mt * 16 + q * 4 + r;
                if (H == 8) {
                    float ps0 = acc[mt][0][r] * as[0] + acc[mt][1][r] * as[1];
                    float ps1 = acc[mt][2][r] * as[2] + acc[mt][3][r] * as[3];
                    float pd0 = acc[mt][0][r] * ad[0] + acc[mt][1][r] * ad[1];
                    float pd1 = acc[mt][2][r] * ad[2] + acc[mt][3][r] * ad[3];
#pragma unroll
                    for (int o = 1; o < 16; o <<= 1) {
                        ps0 += __shfl_xor(ps0, o, 64); ps1 += __shfl_xor(ps1, o, 64);
                        pd0 += __shfl_xor(pd0, o, 64); pd1 += __shfl_xor(pd1, o, 64);
                    }
                    if (mrow == 0 && row < N_NODES) {
                        als[row * 8 + 2 * wv] = ps0 * LOG2E;
                        als[row * 8 + 2 * wv + 1] = ps1 * LOG2E;
                        ald[row * 8 + 2 * wv] = pd0 * LOG2E;
                        ald[row * 8 + 2 * wv + 1] = pd1 * LOG2E;
                    }
                } else {
                    float ps = acc[mt][0][r] * as[0] + acc[mt][1][r] * as[1]
                             + acc[mt][2][r] * as[2] + acc[mt][3][r] * as[3];
                    float pd = acc[mt][0][r] * ad[0] + acc[mt][1][r] * ad[1]
                             + acc[mt][2][r] * ad[2] + acc[mt][3][r] * ad[3];
#pragma unroll
                    for (int o = 1; o < 16; o <<= 1) {
                        ps += __shfl_xor(ps, o, 64); pd += __shfl_xor(pd, o, 64);
                    }
                    if (mrow == 0) {
                        sals[mt * 16 + q * 4 + r][wv] = ps;
                        sald[mt * 16 + q * 4 + r][wv] = pd;
                    }
                }
            }
        }
    }
    __syncthreads();                     // A-tile dead; sals complete
    if (H == 1 && t < 64) {
        const int row = m0 + t;
        if (row < N_NODES) {
            als[row] = (sals[t][0] + sals[t][1] + sals[t][2] + sals[t][3]) * LOG2E;
            ald[row] = (sald[t][0] + sald[t][1] + sald[t][2] + sald[t][3]) * LOG2E;
        }
    }
    float* S = (float*)As + wv * 16 * 68;   // 16 rows x 68 floats, wave-private
    const int prow = lane >> 2, pj = lane & 3;   // pack: lane -> (row-in-tile, uint4 j)
#pragma unroll
    for (int mt = 0; mt < 4; mt++) {
#pragma unroll
        for (int i = 0; i < 4; i++)
#pragma unroll
            for (int r = 0; r < 4; r++)
                S[(q * 4 + r) * 68 + i * 16 + mrow] = acc[mt][i][r];
        // wave-internal LDS ordering: no barrier needed
        const float* cp = S + prow * 68 + pj * 16;
        uint4 o;
        o.x = pk4fp8(cp[0],  cp[1],  cp[2],  cp[3]);
        o.y = pk4fp8(cp[4],  cp[5],  cp[6],  cp[7]);
        o.z = pk4fp8(cp[8],  cp[9],  cp[10], cp[11]);
        o.w = pk4fp8(cp[12], cp[13], cp[14], cp[15]);
        const int row = m0 + mt * 16 + prow;
        if (row < N_NODES)
            ((uint4*)(Y8 + (size_t)row * 64))[wv * 4 + pj] = o;
    }
}

#define UN 4

// layer-1 gather: scalar wid, padded rows (no clamps), exp2 logits, packed-f32 accum
__global__ __launch_bounds__(256) void gat_gather1(
        const int* __restrict__ row_start, const int* __restrict__ srclist,
        const float* __restrict__ als, const float* __restrict__ ald,
        const uint* __restrict__ xw8,                    // fp8 rows, 64 uints/row
        const float* __restrict__ bias,
        ushort* __restrict__ emb1b) {                    // [N][256] bf16
    const int wid = __builtin_amdgcn_readfirstlane(blockIdx.x * 4 + (threadIdx.x >> 6));
    const uint lane = threadIdx.x & 63;
    const uint h = lane >> 3;
    const float ald_n = ald[wid * HEADS_1 + h];
    const int beg = row_start[wid], end = row_start[wid + 1];

    float ex0 = __builtin_amdgcn_exp2f(leaky(als[wid * HEADS_1 + h] + ald_n));
    uint u = xw8[((uint)wid << 6) + lane];
    vf2 lo = __builtin_amdgcn_cvt_pk_f32_fp8((int)u, false);
    vf2 hi = __builtin_amdgcn_cvt_pk_f32_fp8((int)u, true);
    float den = ex0;
    vf2 exv0 = {ex0, ex0};
    vf2 a01 = exv0 * lo, a23 = exv0 * hi;

    for (int i = beg; i < end; i += UN) {
        uint ss[UN]; uint rr[UN]; float ee[UN];
#pragma unroll
        for (int j = 0; j < UN; j++) ss[j] = (uint)srclist[i + j];
#pragma unroll
        for (int j = 0; j < UN; j++) rr[j] = xw8[(ss[j] << 6) + lane];
#pragma unroll
        for (int j = 0; j < UN; j++) ee[j] = als[ss[j] * HEADS_1 + h];
#pragma unroll
        for (int j = 0; j < UN; j++) {
            float ex = __builtin_amdgcn_exp2f(leaky(ee[j] + ald_n));   // sentinel -> 0
            vf2 l2 = __builtin_amdgcn_cvt_pk_f32_fp8((int)rr[j], false);
            vf2 h2 = __builtin_amdgcn_cvt_pk_f32_fp8((int)rr[j], true);
            den += ex;
            vf2 exv = {ex, ex};
            a01 += exv * l2;
            a23 += exv * h2;
        }
    }
    float inv = 1.f / den;
    float4 bv = ((const float4*)bias)[lane];
    float4 r;
    r.x = a01[0] * inv + bv.x; r.y = a01[1] * inv + bv.y;
    r.z = a23[0] * inv + bv.z; r.w = a23[1] * inv + bv.w;
    r.x = r.x > 0.f ? r.x : __expf(r.x) - 1.f;
    r.y = r.y > 0.f ? r.y : __expf(r.y) - 1.f;
    r.z = r.z > 0.f ? r.z : __expf(r.z) - 1.f;
    r.w = r.w > 0.f ? r.w : __expf(r.w) - 1.f;
    uint2 p;
    p.x = (uint)f2bf(r.x) | ((uint)f2bf(r.y) << 16);
    p.y = (uint)f2bf(r.z) | ((uint)f2bf(r.w) << 16);
    ((uint2*)emb1b)[((uint)wid << 6) + lane] = p;
}

// layer-2 gather fused with normalize + fp8 pack of embn
__global__ __launch_bounds__(256) void gat_gather2(
        const int* __restrict__ row_start, const int* __restrict__ srclist,
        const float* __restrict__ als, const float* __restrict__ ald,
        const uint* __restrict__ xw8,                    // fp8 rows, 64 uints/row
        const float* __restrict__ bias,
        const ushort* __restrict__ emb1b,                // [N][256] bf16
        uint* __restrict__ embn8) {                      // [N][512] fp8, 128 uints/row
    const int wid = __builtin_amdgcn_readfirstlane(blockIdx.x * 4 + (threadIdx.x >> 6));
    const uint lane = threadIdx.x & 63;
    const float ald_n = ald[wid];
    const int beg = row_start[wid], end = row_start[wid + 1];

    float ex0 = __builtin_amdgcn_exp2f(leaky(als[wid] + ald_n));
    uint u = xw8[((uint)wid << 6) + lane];
    vf2 lo = __builtin_amdgcn_cvt_pk_f32_fp8((int)u, false);
    vf2 hi = __builtin_amdgcn_cvt_pk_f32_fp8((int)u, true);
    float den = ex0;
    vf2 exv0 = {ex0, ex0};
    vf2 a01 = exv0 * lo, a23 = exv0 * hi;

    for (int i = beg; i < end; i += UN) {
        uint ss[UN]; uint rr[UN]; float ee[UN];
#pragma unroll
        for (int j = 0; j < UN; j++) ss[j] = (uint)srclist[i + j];
#pragma unroll
        for (int j = 0; j < UN; j++) rr[j] = xw8[(ss[j] << 6) + lane];
#pragma unroll
        for (int j = 0; j < UN; j++) ee[j] = als[ss[j]];
#pragma unroll
        for (int j = 0; j < UN; j++) {
            float ex = __builtin_amdgcn_exp2f(leaky(ee[j] + ald_n));   // sentinel -> 0
            vf2 l2 = __builtin_amdgcn_cvt_pk_f32_fp8((int)rr[j], false);
            vf2 h2 = __builtin_amdgcn_cvt_pk_f32_fp8((int)rr[j], true);
            den += ex;
            vf2 exv = {ex, ex};
            a01 += exv * l2;
            a23 += exv * h2;
        }
    }
    float inv = 1.f / den;
    float4 bv = ((const float4*)bias)[lane];
    float4 e2;
    e2.x = a01[0] * inv + bv.x; e2.y = a01[1] * inv + bv.y;
    e2.z = a23[0] * inv + bv.z; e2.w = a23[1] * inv + bv.w;
    uint2 u1 = ((const uint2*)emb1b)[((uint)wid << 6) + lane];
    float4 e1;
    e1.x = bfl(u1.x); e1.y = bfh(u1.x); e1.z = bfl(u1.y); e1.w = bfh(u1.y);

    float ssum = e1.x * e1.x + e1.y * e1.y + e1.z * e1.z + e1.w * e1.w
               + e2.x * e2.x + e2.y * e2.y + e2.z * e2.z + e2.w * e2.w;
#pragma unroll
    for (int o = 32; o > 0; o >>= 1) ssum += __shfl_xor(ssum, o, 64);
    float innv = 1.f / fmaxf(sqrtf(ssum), 1e-8f);

    uint p1 = pk4fp8(e1.x * innv, e1.y * innv, e1.z * innv, e1.w * innv);
    uint p2 = pk4fp8(e2.x * innv, e2.y * innv, e2.z * innv, e2.w * innv);
    embn8[((uint)wid << 7) + lane] = p1;        // dims 0..255   (emb1 part)
    embn8[((uint)wid << 7) + 64 + lane] = p2;   // dims 256..511 (emb2 part)
}

// ---------------- MFMA contrastive loss (fp8) ----------------

#define ANCH 16                         // anchors per block (walk segment)
#define MAXROWS (ANCH + 2 * WINDOW)     // 26 LDS rows max
#define ROWU 130                        // 520 B row stride (2 banks mod 32, conflict-free)

// one block per 16-anchor segment, 768 threads = 12 waves, one tile-job per wave.
__global__ __launch_bounds__(768) void loss_mfma_kernel(
        const uint* __restrict__ embn8,    // [N][512] fp8, 128 uints/row
        const int* __restrict__ walks, const int* __restrict__ negs,
        float* __restrict__ out) {
    __shared__ __align__(16) uint srows8[MAXROWS * ROWU];   // 13.5 KB
    __shared__ int wids[MAXROWS];
    __shared__ int snid[160];
    __shared__ float possum[16];
    __shared__ float negsum[16];
    const int blk = blockIdx.x;
    const int b = blk >> 2;                  // walk
    const int l0 = (blk & 3) * ANCH;         // first anchor of segment
    const int base = (l0 - WINDOW) > 0 ? (l0 - WINDOW) : 0;
    const int hi = (l0 + ANCH - 1 + WINDOW) < (WALK_LEN - 1) ? (l0 + ANCH - 1 + WINDOW) : (WALK_LEN - 1);
    const int cnt = hi - base + 1;           // 21..26
    const int t = threadIdx.x;
    const int w = __builtin_amdgcn_readfirstlane(t >> 6);   // 0..11 = this wave's job
    const int lane = t & 63;
    if (t < cnt) wids[t] = walks[b * WALK_LEN + base + t];
    if (t >= 64 && t < 64 + 160) snid[t - 64] = negs[(b * WALK_LEN + l0) * NEG_S + (t - 64)];
    if (t >= 224 && t < 240) { possum[t - 224] = 0.f; negsum[t - 224] = 0.f; }
    __syncthreads();
    for (int r = w; r < cnt; r += 12)
        ((uint2*)(srows8 + r * ROWU))[lane] = ((const uint2*)(embn8 + ((uint)wids[r] << 7)))[lane];
    __syncthreads();

    const int mrow = lane & 15, q = lane >> 4;
    const int arow = (l0 - base) + mrow;     // LDS row of anchor #mrow
    const char* embc = (const char*)embn8;   // byte rows, stride 512
    const char* ap = (const char*)(srows8 + arow * ROWU) + q * 8;

    const int job = w;
    f32x4 acc0 = {0.f, 0.f, 0.f, 0.f};
    f32x4 acc1 = {0.f, 0.f, 0.f, 0.f};
    if (job < 10) {
        // ---- neg tile: cands c = 16*job .. +15, col = mrow ----
        const int c = job * 16 + mrow;
        const int node = snid[c];
        const char* bp = embc + (((uint)node << 9) + (uint)(q * 8));
#pragma unroll
        for (int k0 = 0; k0 < 256; k0 += 32) {
            i64_t a0 = *(const i64_t*)(ap + k0);
            i64_t b0 = *(const i64_t*)(bp + k0);
            acc0 = __builtin_amdgcn_mfma_f32_16x16x32_fp8_fp8(a0, b0, acc0, 0, 0, 0);
            i64_t a1 = *(const i64_t*)(ap + k0 + 256);
            i64_t b1 = *(const i64_t*)(bp + k0 + 256);
            acc1 = __builtin_amdgcn_mfma_f32_16x16x32_fp8_fp8(a1, b1, acc1, 0, 0, 0);
        }
        const int owner = c / 10;
#pragma unroll
        for (int reg = 0; reg < 4; reg++) {
            const int a_local = q * 4 + reg;
            float e = 0.f;
            if (owner == a_local) {
                const int l_a = l0 + a_local;
                bool msk = false;
#pragma unroll
                for (int dj = -WINDOW; dj <= WINDOW; dj++) {
                    if (dj == 0) continue;
                    int p = l_a + dj;
                    if (p >= 0 && p < WALK_LEN && wids[p - base] == node) msk = true;
                }
                if (!msk) e = __expf((acc0[reg] + acc1[reg]) * INV_TEMP);
            }
#pragma unroll
            for (int o = 1; o < 16; o <<= 1) e += __shfl_xor(e, o, 64);
            if (mrow == 0 && e != 0.f) atomicAdd(&negsum[a_local], e);
        }
    } else {
        // ---- pos tile: LDS rows r = 16*(job-10) .. +15 ----
        const int r = (job - 10) * 16 + mrow;
        const int rc = r < (cnt - 1) ? r : (cnt - 1);
        const char* bp = (const char*)(srows8 + rc * ROWU) + q * 8;
#pragma unroll
        for (int k0 = 0; k0 < 256; k0 += 32) {
            i64_t a0 = *(const i64_t*)(ap + k0);
            i64_t b0 = *(const i64_t*)(bp + k0);
            acc0 = __builtin_amdgcn_mfma_f32_16x16x32_fp8_fp8(a0, b0, acc0, 0, 0, 0);
            i64_t a1 = *(const i64_t*)(ap + k0 + 256);
            i64_t b1 = *(const i64_t*)(bp + k0 + 256);
            acc1 = __builtin_amdgcn_mfma_f32_16x16x32_fp8_fp8(a1, b1, acc1, 0, 0, 0);
        }
        const int pg = base + r;                 // walk position of this row
#pragma unroll
        for (int reg = 0; reg < 4; reg++) {
            const int a_local = q * 4 + reg;
            const int l_a = l0 + a_local;
            const int d = pg - l_a;
            bool use = (r < cnt) && (d != 0) && (d >= -WINDOW) && (d <= WINDOW);
            float e = use ? __expf((acc0[reg] + acc1[reg]) * INV_TEMP) : 0.f;
#pragma unroll
            for (int o = 1; o < 16; o <<= 1) e += __shfl_xor(e, o, 64);
            if (mrow == 0 && e != 0.f) atomicAdd(&possum[a_local], e);
        }
    }
    __syncthreads();
    if (t < 16) {
        float term = logf(1.f + negsum[t] / possum[t]);   // possum > 0 always
#pragma unroll
        for (int o = 8; o > 0; o >>= 1) term += __shfl_xor(term, o, 64);
        if (t == 0) atomicAdd(out, term);
    }
}

extern "C" void kernel_launch(void* const* d_in, const int* in_sizes, int n_in,
                              void* d_out, int out_size, void* d_ws, size_t ws_size,
                              hipStream_t stream) {
    const float* x      = (const float*)d_in[0];
    const int*   ei     = (const int*)d_in[1];
    const int*   walks  = (const int*)d_in[2];
    const int*   negs   = (const int*)d_in[3];
    const float* W1     = (const float*)d_in[4];
    const float* a_src1 = (const float*)d_in[5];
    const float* a_dst1 = (const float*)d_in[6];
    const float* b1     = (const float*)d_in[7];
    const float* W2     = (const float*)d_in[8];
    const float* a_src2 = (const float*)d_in[9];
    const float* a_dst2 = (const float*)d_in[10];
    const float* b2     = (const float*)d_in[11];
    float* out = (float*)d_out;

    float* ws = (float*)d_ws;
    size_t off = 0;
    // every region aligned to 1024 B (256 floats) so row starts stay cache-line aligned
#define ALIGN_OFF off = (off + 255) & ~(size_t)255
    float* r_xw8   = ws + off; off += (size_t)(N_NODES + 1) * 64;  ALIGN_OFF;  // [N+1][256] fp8 (sentinel row)
    float* r_emb1b = ws + off; off += (size_t)N_PAD * 128;         ALIGN_OFF;  // [Npad][256] bf16
    float* r_embn8 = ws + off; off += (size_t)N_NODES * 128;       ALIGN_OFF;  // [N][512] fp8
    float* r_xb    = ws + off; off += (size_t)N_PAD * 64;          ALIGN_OFF;  // [Npad][128] bf16
    float* r_wt1   = ws + off; off += 256 * 64;                    ALIGN_OFF;  // [256][128] bf16
    float* r_wt2   = ws + off; off += 256 * 128;                   ALIGN_OFF;  // [256][256] bf16
    float* als1  = ws + off; off += (N_NODES + 1) * HEADS_1;       ALIGN_OFF;  // sentinel row
    float* ald1  = ws + off; off += N_NODES * HEADS_1;             ALIGN_OFF;
    float* als2  = ws + off; off += N_NODES + 1;                   ALIGN_OFF;  // sentinel
    float* ald2  = ws + off; off += N_NODES;                       ALIGN_OFF;
    int* deg       = (int*)(ws + off); off += N_NODES;             ALIGN_OFF;
    int* excl      = (int*)(ws + off); off += N_NODES;             ALIGN_OFF;
    int* bsum      = (int*)(ws + off); off += 256;                 ALIGN_OFF;
    int* row_start = (int*)(ws + off); off += N_NODES + 1;         ALIGN_OFF;
    int* cursor    = (int*)(ws + off); off += N_NODES;             ALIGN_OFF;
    int* srclist   = (int*)(ws + off); off += E_PAD;               ALIGN_OFF;
    uint*   xw8   = (uint*)r_xw8;
    ushort* emb1b = (ushort*)r_emb1b;
    uint*   embn8 = (uint*)r_embn8;
    ushort* xb    = (ushort*)r_xb;
    ushort* wt1   = (ushort*)r_wt1;
    ushort* wt2   = (ushort*)r_wt2;

    hipMemsetAsync(out, 0, sizeof(float) * out_size, stream);
    hipMemsetAsync(deg, 0, sizeof(int) * N_NODES, stream);
    hipMemsetAsync(cursor, 0, sizeof(int) * N_NODES, stream);

    // ---- CSR build (padded rows, sentinel-filled; shared by both layers) ----
    deg_kernel<<<(E_EDGES + 255) / 256, 256, 0, stream>>>(ei, deg);
    scan_a<<<SCAN_BLOCKS, 256, 0, stream>>>(deg, excl, bsum);
    scan_b<<<1, 256, 0, stream>>>(bsum);
    scan_c2<<<SCAN_BLOCKS, 256, 0, stream>>>(deg, excl, bsum, row_start);
    fill_sent_kernel<<<(E_PAD + 255) / 256, 256, 0, stream>>>(srclist, E_PAD);
    bucket_kernel<<<(E_EDGES + 255) / 256, 256, 0, stream>>>(ei, row_start, cursor, srclist);
    sent_al_kernel<<<1, 64, 0, stream>>>(als1, als2);

    // ---- bf16 conversions ----
    f32_to_bf16_kernel<<<(N_NODES * FDIM_IN / 4 + 255) / 256, 256, 0, stream>>>(
        x, (uint*)xb, N_NODES * FDIM_IN / 4);
    wtrans_kernel<<<(256 * 128 + 255) / 256, 256, 0, stream>>>(W1, wt1, 128);
    wtrans_kernel<<<(256 * 256 + 255) / 256, 256, 0, stream>>>(W2, wt2, 256);

    // ---- layer 1 (heads=8, hid=32), fused als/ald epilogue ----
    mfma_gemm64<128, HEADS_1><<<N_PAD / 64, 256, 0, stream>>>(
        xb, wt1, xw8, a_src1, a_dst1, als1, ald1);
    gat_gather1<<<N_NODES / 4, 256, 0, stream>>>(
        row_start, srclist, als1, ald1, xw8, b1, emb1b);

    // ---- layer 2 (heads=1, hid=256), fused als/ald + normalize + fp8 pack ----
    mfma_gemm64<256, 1><<<N_PAD / 64, 256, 0, stream>>>(
        emb1b, wt2, xw8, a_src2, a_dst2, als2, ald2);
    gat_gather2<<<N_NODES / 4, 256, 0, stream>>>(
        row_start, srclist, als2, ald2, xw8, b2, emb1b, embn8);

    // ---- contrastive loss (fp8 MFMA, one job per wave) ----
    loss_mfma_kernel<<<NUM_WALKS * 4, 768, 0, stream>>>(embn8, walks, negs, out);
}